// Round 8
// baseline (231.019 us; speedup 1.0000x reference)
//
#include <hip/hip_runtime.h>
#include <math.h>

typedef __bf16  bf16x8 __attribute__((ext_vector_type(8)));
typedef float   f32x4  __attribute__((ext_vector_type(4)));

// async global->LDS, 16B per lane. Pass per-lane dest (= base + lane*16).
#define GLD_LDS16(dst, src)                                                      \
    __builtin_amdgcn_global_load_lds(                                            \
        (const __attribute__((address_space(1))) unsigned int*)(src),            \
        (__attribute__((address_space(3))) unsigned int*)(dst), 16, 0, 0)

// ---------------------------------------------------------------------------
// Kernel T v6: x[b,ci,h,w] fp32 -> xT[b,h,w,ci] bf16 + fused pool partials.
// v4 (dense writes, strided reads) == v5 (dense reads, strided writes) in
// total time => each bound by its own strided side at ~1 TB/s. v6 is dense
// on BOTH sides: block = (b, h-quad) with ALL 256 ci, 512 thr, 136KB LDS.
//  reads : wave-instr = x[b,ci,h0:h0+4,0:64] = 1KB contiguous
//  writes: lanes 0..31 = one full 512B ci-row, 32..63 = next row -> 1KB/instr
//  LDS   : phase-L b128 full-density; phase-S b32 reads conflicted but the
//          LDS pipe (~17K cyc/blk) hides under ~40K cyc of HBM traffic.
// psum partials identical to v5 (slot = hq*4+hl); routing unchanged.
// ---------------------------------------------------------------------------
__global__ __launch_bounds__(512, 1) void transpose_kernel(const float* __restrict__ x,
                                                           __bf16* __restrict__ xT,
                                                           float* __restrict__ psum) {
    __shared__ unsigned int lp[4][128][68];  // [h][ci-pair][w pad 64->68]
    const int hq = blockIdx.x;               // 0..15
    const int b  = blockIdx.y;               // 0..15
    const int h0 = hq * 4;
    const int t    = threadIdx.x;
    const int lane = t & 63, wv = t >> 6;    // wv 0..7
    const int hl = lane >> 4;                // 0..3
    const int w4 = lane & 15;                // 0..15

    const float* xb = x + (((size_t)b * 256 * 64) + (h0 + hl)) * 64 + w4 * 4;
    // each wave owns 16 ci-pairs; 4 batches of 4 pairs (8 loads in flight)
    for (int bat = 0; bat < 4; ++bat) {
        float4 va[4], vc[4];
#pragma unroll
        for (int u = 0; u < 4; ++u) {
            const int p = wv * 16 + bat * 4 + u;      // wave-uniform pair
            va[u] = *(const float4*)(xb + (size_t)(2 * p)     * 4096);
            vc[u] = *(const float4*)(xb + (size_t)(2 * p + 1) * 4096);
        }
#pragma unroll
        for (int u = 0; u < 4; ++u) {
            const int p = wv * 16 + bat * 4 + u;
            const float4 a = va[u], c = vc[u];
            union { __bf16 hh[2]; unsigned int u32; } p0, p1, p2, p3;
            p0.hh[0] = (__bf16)a.x; p0.hh[1] = (__bf16)c.x;
            p1.hh[0] = (__bf16)a.y; p1.hh[1] = (__bf16)c.y;
            p2.hh[0] = (__bf16)a.z; p2.hh[1] = (__bf16)c.z;
            p3.hh[0] = (__bf16)a.w; p3.hh[1] = (__bf16)c.w;
            uint4 v = {p0.u32, p1.u32, p2.u32, p3.u32};
            *(uint4*)&lp[hl][p][w4 * 4] = v;          // b128 full-density
            // pool partials: reduce across the 16 w4 lanes of each hl group
            float sA = a.x + a.y + a.z + a.w;
            float sC = c.x + c.y + c.z + c.w;
#pragma unroll
            for (int m = 1; m <= 8; m <<= 1) {
                sA += __shfl_xor(sA, m, 64);
                sC += __shfl_xor(sC, m, 64);
            }
            if (w4 == 0) {
                *(float2*)&psum[(((size_t)b * 64) + h0 + hl) * 256 + 2 * p] =
                    make_float2(sA, sC);
            }
        }
    }
    __syncthreads();
    // phase S: lanes 0..31 write one full 512B ci-row, 32..63 the next row
#pragma unroll
    for (int j = 0; j < 16; ++j) {
        const int cid = j * 512 + t;
        const int pos = cid >> 5;            // 0..255 : hh(2b) x w(6b)
        const int pc  = cid & 31;            // ci-octet 0..31
        const int hh = pos >> 6, w = pos & 63;
        uint4 v;
        v.x = lp[hh][pc * 4 + 0][w];
        v.y = lp[hh][pc * 4 + 1][w];
        v.z = lp[hh][pc * 4 + 2][w];
        v.w = lp[hh][pc * 4 + 3][w];
        *(uint4*)(xT + (((size_t)(b * 64 + h0 + hh) * 64 + w) * 256) + pc * 8) = v;
    }
}

// ---------------------------------------------------------------------------
// Kernel R v2: one block per b (16 blocks x 256 thr).
// 1) pooled_b[ci] = sum_slot psum[b][slot][ci] / 4096   (coalesced over ci)
// 2) zl/zt[n] via LDS + half-wave shuffle reduce
// 3) 4 threads compute lambda*R -> slg[b][n][p][12]
// ---------------------------------------------------------------------------
__global__ __launch_bounds__(256) void routing_kernel(
    const float* __restrict__ psum, const float* __restrict__ w_lambda,
    const float* __restrict__ w_theta, float* __restrict__ slg) {
    const int b = blockIdx.x, t = threadIdx.x;
    float s = 0.f;
    const float* p = psum + (size_t)b * 16384 + t;
#pragma unroll 8
    for (int h = 0; h < 64; ++h) s += p[h * 256];
    const float pv = s * (1.f / 4096.f);
    __shared__ float red[8][256];
    float4 wl = *(const float4*)&w_lambda[t * 4];
    float4 wt = *(const float4*)&w_theta[t * 4];
    red[0][t] = pv * wl.x; red[1][t] = pv * wl.y;
    red[2][t] = pv * wl.z; red[3][t] = pv * wl.w;
    red[4][t] = pv * wt.x; red[5][t] = pv * wt.y;
    red[6][t] = pv * wt.z; red[7][t] = pv * wt.w;
    __syncthreads();
    __shared__ float zv[8];
    const int rrow = t >> 5, i = t & 31;   // 8 rows x 32 threads
    float acc = red[rrow][i]       + red[rrow][i + 32]
              + red[rrow][i + 64]  + red[rrow][i + 96]
              + red[rrow][i + 128] + red[rrow][i + 160]
              + red[rrow][i + 192] + red[rrow][i + 224];
#pragma unroll
    for (int m = 16; m >= 1; m >>= 1) acc += __shfl_xor(acc, m, 64);
    if (i == 0) zv[rrow] = acc;
    __syncthreads();
    if (t < 4) {
        const int n = t;
        float zl = zv[n], zt = zv[4 + n];
        float lam = 1.f / (1.f + expf(-zl));
        float th  = 3.14159265358979323846f * (zt / (1.f + fabsf(zt)));
        float xc = cosf(th), ys = sinf(th);
        float a = xc - ys, bb = xc * ys, c = xc + ys;
        float R[9][9];
#pragma unroll
        for (int ii = 0; ii < 9; ii++)
#pragma unroll
            for (int jj = 0; jj < 9; jj++) R[ii][jj] = 0.f;
        if (th >= 0.f) {
            R[0][0] = a;       R[0][1] = 1 - a;
            R[1][1] = xc - bb; R[1][2] = bb;       R[1][4] = 1 - c + bb; R[1][5] = ys - bb;
            R[2][2] = a;       R[2][5] = 1 - a;
            R[3][0] = bb;      R[3][1] = ys - bb;  R[3][3] = xc - bb;    R[3][4] = 1 - c + bb;
            R[4][4] = 1.f;
            R[5][4] = 1 - c + bb; R[5][5] = xc - bb; R[5][7] = ys - bb;  R[5][8] = bb;
            R[6][3] = 1 - a;   R[6][6] = a;
            R[7][3] = ys - bb; R[7][4] = 1 - c + bb; R[7][6] = bb;       R[7][7] = xc - bb;
            R[8][7] = 1 - a;   R[8][8] = a;
        } else {
            R[0][0] = c;       R[0][3] = 1 - c;
            R[1][0] = -bb;     R[1][1] = xc + bb;  R[1][3] = bb - ys;    R[1][4] = 1 - a - bb;
            R[2][1] = 1 - c;   R[2][2] = c;
            R[3][3] = xc + bb; R[3][4] = 1 - a - bb; R[3][6] = -bb;      R[3][7] = bb - ys;
            R[4][4] = 1.f;
            R[5][1] = bb - ys; R[5][2] = -bb;      R[5][4] = 1 - a - bb; R[5][5] = xc + bb;
            R[6][6] = c;       R[6][7] = 1 - c;
            R[7][4] = 1 - a - bb; R[7][5] = bb - ys; R[7][7] = xc + bb;  R[7][8] = -bb;
            R[8][5] = 1 - c;   R[8][8] = c;
        }
        float* o = slg + ((size_t)(b * 4 + n) * 9) * 12;
#pragma unroll
        for (int pp = 0; pp < 9; pp++) {
#pragma unroll
            for (int q = 0; q < 9; q++) o[pp * 12 + q] = lam * R[pp][q];
            o[pp * 12 + 9] = o[pp * 12 + 10] = o[pp * 12 + 11] = 0.f;
        }
    }
}

// ---------------------------------------------------------------------------
// Kernel C v3: rotated weights. rwq[b][tap][co][ci] bf16.
// Grid 1024 (co x ci-quarter) -> 4 blocks/CU, 16 waves/CU.
// Thread = (ci_local 0..63, b-group 0..3); each does 4 b x 9 p.
// ---------------------------------------------------------------------------
__global__ __launch_bounds__(256) void rotw_kernel(
    const float* __restrict__ weight, const float* __restrict__ slg,
    __bf16* __restrict__ rwq) {
    __shared__ __attribute__((aligned(16))) float sl[16][4][9][12];
    const int lin = blockIdx.x;
    const int co  = lin >> 2;
    const int ciq = lin & 3;
    const int t   = threadIdx.x;
    const int ci  = ciq * 64 + (t & 63);
    const int bg  = t >> 6;               // 0..3
    for (int i = t; i < 1728; i += 256)    // 6912 floats = 1728 float4
        ((float4*)sl)[i] = ((const float4*)slg)[i];
    float4 wa[4], wb[4];
    float  wc[4];
#pragma unroll
    for (int n = 0; n < 4; n++) {
        const float* wp = weight + ((size_t)n * 256 + co) * 2304 + (size_t)ci * 9;
        wa[n] = make_float4(wp[0], wp[1], wp[2], wp[3]);
        wb[n] = make_float4(wp[4], wp[5], wp[6], wp[7]);
        wc[n] = wp[8];
    }
    __syncthreads();
#pragma unroll
    for (int bo = 0; bo < 4; bo++) {
        const int b = bg * 4 + bo;
#pragma unroll
        for (int p = 0; p < 9; p++) {
            float s = 0.f;
#pragma unroll
            for (int n = 0; n < 4; n++) {
                float4 sa = *(const float4*)&sl[b][n][p][0];
                float4 sb = *(const float4*)&sl[b][n][p][4];
                float  sc = sl[b][n][p][8];
                s += sa.x * wa[n].x + sa.y * wa[n].y + sa.z * wa[n].z + sa.w * wa[n].w
                   + sb.x * wb[n].x + sb.y * wb[n].y + sb.z * wb[n].z + sb.w * wb[n].w
                   + sc * wc[n];
            }
            rwq[(((size_t)b * 9 + p) * 256 + co) * 256 + ci] = (__bf16)s;
        }
    }
}

// ---------------------------------------------------------------------------
// Kernel D: implicit-GEMM conv + fused BN/ReLU — VERBATIM R0 (83.5us proven).
// 2 blocks/CU co-resident (8 waves/CU) provides the overlap; R2/R3 showed
// explicit double-buffering at 1 blk/CU loses the TLP and regresses.
// ---------------------------------------------------------------------------
__global__ __launch_bounds__(256, 2) void conv_kernel(
    const __bf16* __restrict__ xT, const __bf16* __restrict__ rwq,
    const float* __restrict__ bn_gamma, const float* __restrict__ bn_beta,
    const float* __restrict__ bn_mean,  const float* __restrict__ bn_var,
    float* __restrict__ out) {
    __shared__ __attribute__((aligned(16))) __bf16 xs[10][4][66][8];
    __shared__ __attribute__((aligned(16))) __bf16 as9[9][4][66][8];
    __shared__ float bns[64], bnh[64];

    const int t    = threadIdx.x;
    const int lane = t & 63;
    const int wv   = t >> 6;
    const int l15  = lane & 15;
    const int kq4  = lane >> 4;

    const int lin  = blockIdx.x;
    const int r    = lin & 7;
    const int k    = lin >> 3;
    const int b    = (r << 1) | (k >> 5);
    const int inner = k & 31;
    const int co0  = (inner & 3) << 6;
    const int h0   = (inner >> 2) << 3;

    if (t < 64) {
        float inv = rsqrtf(bn_var[co0 + t] + 1e-5f);
        float sc = bn_gamma[co0 + t] * inv;
        bns[t] = sc;
        bnh[t] = bn_beta[co0 + t] - bn_mean[co0 + t] * sc;
    }

    f32x4 acc[2][4][4];
#pragma unroll
    for (int rr = 0; rr < 2; rr++)
#pragma unroll
        for (int m = 0; m < 4; m++)
#pragma unroll
            for (int n = 0; n < 4; n++) acc[rr][m][n] = (f32x4){0.f, 0.f, 0.f, 0.f};

    const uint4 zero4 = {0u, 0u, 0u, 0u};
    if (t < 40) {
        int rr = t >> 2, kq = t & 3;
        *(uint4*)&xs[rr][kq][0][0]  = zero4;
        *(uint4*)&xs[rr][kq][65][0] = zero4;
    }

    for (int ci0 = 0; ci0 < 256; ci0 += 32) {
        __syncthreads();                 // prev chunk's compute done before overwrite
#pragma unroll
        for (int u = wv * 10; u < wv * 10 + 10; u++) {
            int rr = u >> 2, kq = u & 3;
            int hh = h0 - 1 + rr;
            if (hh >= 0 && hh < 64) {
                const __bf16* src = xT + (((size_t)(b * 64 + hh) * 64 + lane) * 256 + ci0 + kq * 8);
                GLD_LDS16(&xs[rr][kq][1 + lane][0], src);
            } else {
                *(uint4*)&xs[rr][kq][1 + lane][0] = zero4;
            }
        }
#pragma unroll
        for (int u = wv * 9; u < wv * 9 + 9; u++) {
            int tap = u >> 2, kq = u & 3;
            const __bf16* src = rwq +
                ((((size_t)b * 9 + tap) * 256 + co0 + lane) * 256 + ci0 + kq * 8);
            GLD_LDS16(&as9[tap][kq][lane][0], src);
        }
        __syncthreads();                 // drains DMA; xs + as9 ready
#pragma unroll
        for (int tap = 0; tap < 9; tap++) {
            const int dh = tap / 3, dw = tap % 3;
            bf16x8 af[4];
#pragma unroll
            for (int m = 0; m < 4; m++)
                af[m] = *(const bf16x8*)&as9[tap][kq4][m * 16 + l15][0];
#pragma unroll
            for (int rr = 0; rr < 2; rr++) {
                const int hl = wv + rr * 4;
#pragma unroll
                for (int nt = 0; nt < 4; nt++) {
                    bf16x8 bfr = *(const bf16x8*)&xs[hl + dh][kq4][nt * 16 + l15 + dw][0];
#pragma unroll
                    for (int m = 0; m < 4; m++)
                        acc[rr][m][nt] = __builtin_amdgcn_mfma_f32_16x16x32_bf16(
                            af[m], bfr, acc[rr][m][nt], 0, 0, 0);
                }
            }
        }
    }

    // epilogue: BN + ReLU. D layout: row(co) = kq4*4+reg, col(w) = l15
#pragma unroll
    for (int rr = 0; rr < 2; rr++) {
        const int h = h0 + wv + rr * 4;
#pragma unroll
        for (int m = 0; m < 4; m++) {
#pragma unroll
            for (int reg = 0; reg < 4; reg++) {
                int col = m * 16 + kq4 * 4 + reg;        // local co 0..63
                float sc = bns[col], sh = bnh[col];
                int co = co0 + col;
#pragma unroll
                for (int nt = 0; nt < 4; nt++) {
                    int w = nt * 16 + l15;
                    float v = acc[rr][m][nt][reg] * sc + sh;
                    out[(((size_t)b * 256 + co) * 64 + h) * 64 + w] = v > 0.f ? v : 0.f;
                }
            }
        }
    }
}

// ---------------------------------------------------------------------------
extern "C" void kernel_launch(void* const* d_in, const int* in_sizes, int n_in,
                              void* d_out, int out_size, void* d_ws, size_t ws_size,
                              hipStream_t stream) {
    const float* x        = (const float*)d_in[0];
    const float* weight   = (const float*)d_in[1];
    const float* w_lambda = (const float*)d_in[2];
    const float* w_theta  = (const float*)d_in[3];
    const float* bn_gamma = (const float*)d_in[4];
    const float* bn_beta  = (const float*)d_in[5];
    const float* bn_mean  = (const float*)d_in[6];
    const float* bn_var   = (const float*)d_in[7];
    float* out = (float*)d_out;

    char* ws = (char*)d_ws;
    float*  slg     = (float*)(ws + 16384);             // 27.6KB (16*4*9*12 f)
    __bf16* xT      = (__bf16*)(ws + 49152);            // 33.5 MB
    __bf16* rwq     = (__bf16*)(ws + 49152 + 33554432); // 18.9 MB
    float*  psum    = out;   // 1MB scratch in d_out; conv overwrites it later

    transpose_kernel<<<dim3(16, 16), 512, 0, stream>>>(x, xT, psum);
    routing_kernel<<<16, 256, 0, stream>>>(psum, w_lambda, w_theta, slg);
    rotw_kernel<<<1024, 256, 0, stream>>>(weight, slg, rwq);
    conv_kernel<<<512, 256, 0, stream>>>(xT, rwq,
                                         bn_gamma, bn_beta, bn_mean, bn_var, out);
}